// Round 1
// baseline (251.148 us; speedup 1.0000x reference)
//
#include <hip/hip_runtime.h>

// BERTEmbedding: out[b,v,e] = (s0*flux_w[v,e] + flux_b[v,e])
//                           + (s2*time_w[v,e] + time_b[v,e])
//                           + PE(s1)[e]   (interleaved sin/cos)
// B=16, V=4096, E=768, fp32.
#define BB 16
#define VV 4096
#define EE 768
#define E4 (EE / 4)          // 192 float4 columns per row
#define BLOCK 256
#define GRID 1536            // 6 blocks/CU * 256 CU -> ALL blocks co-resident, no tail
#define SPAN (GRID * BLOCK)  // 393216 threads; total columns 786432 = exactly 2 per thread

typedef float f4 __attribute__((ext_vector_type(4)));

// One thread owns a (v, e4) column: weight/bias float4s are loaded from HBM
// exactly once into registers, then the thread loops over all B=16 batch rows.
// Stores stay perfectly coalesced (consecutive lanes -> consecutive e).
// 192 float4-threads per v-row = 3 waves; 64-aligned wave ranges nest inside
// 192-column rows, so v is wave-uniform -> readfirstlane scalarizes the
// sequence loads (s_load through K$).
//
// This round:
//  - balanced grid: 1536 blocks, 2 sequential columns per thread (v and v+2048);
//    __launch_bounds__(256,6) caps VGPR ~84 so all 6 blocks/CU are resident ->
//    no second dispatch wave, no drain tail.
//  - non-temporal stores: output is a 201 MB write-once stream; don't cycle it
//    through L2.
__global__ __launch_bounds__(BLOCK, 6) void bert_embed_kernel(
    const float* __restrict__ seq,     // [B, V, 3]
    const float* __restrict__ flux_w,  // [V, E]
    const float* __restrict__ flux_b,  // [V, E]
    const float* __restrict__ time_w,  // [V, E]
    const float* __restrict__ time_b,  // [V, E]
    float* __restrict__ out)           // [B, V, E]
{
    int tid = blockIdx.x * BLOCK + threadIdx.x;   // [0, SPAN)
    int e4  = tid % E4;
    int v0  = tid / E4;                           // [0, 2048); second column is v0+2048

    // div_term[i] = exp(2i * (-ln(10000)/E)). This thread needs pair indices
    // 2*e4 (-> elements 4e4, 4e4+1) and 2*e4+1 (-> 4e4+2, 4e4+3).
    // Fold 1/(2*pi) in: v_sin_f32/v_cos_f32 take REVOLUTIONS (cdna4_isa §3).
    // e4 identical for both columns (SPAN % E4 == 0) -> compute once.
    const float C1     = -0.011992630692677323f;   // -ln(10000)/768
    const float INV2PI = 0.15915494309189535f;
    float d0 = __expf((float)(4 * e4) * C1) * INV2PI;
    float d1 = __expf((float)(4 * e4 + 2) * C1) * INV2PI;

#pragma unroll 1   // sequential columns: keeps live weights at one column's worth
    for (int rep = 0; rep < 2; ++rep) {
        int v = __builtin_amdgcn_readfirstlane(v0 + rep * (SPAN / E4));  // +2048

        const size_t we = (size_t)v * EE + (size_t)e4 * 4;
        f4 fw = *(const f4*)(flux_w + we);
        f4 tw = *(const f4*)(time_w + we);
        f4 fb = *(const f4*)(flux_b + we);
        f4 tb = *(const f4*)(time_b + we);
        f4 cb = fb + tb;   // combined bias: out = s0*fw + s2*tw + cb + pe

        const float* sp = seq + (size_t)v * 3;   // wave-uniform (scalar) address
        float* op = out + we;

#pragma unroll
        for (int b = 0; b < BB; ++b) {
            float s0 = sp[0];   // flux channel
            float s1 = sp[1];   // passend channel
            float s2 = sp[2];   // time channel

            float r0  = s1 * d0;
            float r1  = s1 * d1;
            float sn0 = __builtin_amdgcn_sinf(r0);   // v_sin_f32 (revolutions)
            float cs0 = __builtin_amdgcn_cosf(r0);
            float sn1 = __builtin_amdgcn_sinf(r1);
            float cs1 = __builtin_amdgcn_cosf(r1);

            f4 o;
            o.x = fmaf(s0, fw.x, fmaf(s2, tw.x, cb.x)) + sn0;
            o.y = fmaf(s0, fw.y, fmaf(s2, tw.y, cb.y)) + cs0;
            o.z = fmaf(s0, fw.z, fmaf(s2, tw.z, cb.z)) + sn1;
            o.w = fmaf(s0, fw.w, fmaf(s2, tw.w, cb.w)) + cs1;
            __builtin_nontemporal_store(o, (f4*)op);  // 201 MB write-once stream

            sp += (size_t)VV * 3;      // next batch row of sequence
            op += (size_t)VV * EE;     // next batch slab of output
        }
    }
}

extern "C" void kernel_launch(void* const* d_in, const int* in_sizes, int n_in,
                              void* d_out, int out_size, void* d_ws, size_t ws_size,
                              hipStream_t stream) {
    const float* seq = (const float*)d_in[0];
    const float* fw  = (const float*)d_in[1];
    const float* fb  = (const float*)d_in[2];
    const float* tw  = (const float*)d_in[3];
    const float* tb  = (const float*)d_in[4];
    float* out = (float*)d_out;

    bert_embed_kernel<<<GRID, BLOCK, 0, stream>>>(seq, fw, fb, tw, tb, out);
}

// Round 3
// 244.219 us; speedup vs baseline: 1.0284x; 1.0284x over previous
//
#include <hip/hip_runtime.h>

// BERTEmbedding: out[b,v,e] = (s0*flux_w[v,e] + flux_b[v,e])
//                           + (s2*time_w[v,e] + time_b[v,e])
//                           + PE(s1)[e]   (interleaved sin/cos)
// B=16, V=4096, E=768, fp32.
//
// ROUND 2: resubmit of round 1's discriminating experiment (round-1 bench
// died to a container-acquisition failure, not a kernel verdict).
// Pure streaming layout, maximally isomorphic to the harness's 6.5 TB/s
// fillBuffer kernel: one monotone, linear write frontier (each block writes
// a contiguous 4 KB chunk per iteration, consecutive blocks adjacent).
// Weights are re-read per batch slab instead of register-cached: the 50 MB
// weight working set is L3-resident (256 MiB Infinity Cache), so HBM FETCH
// stays ~51 MB compulsory.
#define BB 16
#define VV 4096
#define EE 768
#define E4 (EE / 4)              // 192 float4 columns per row
#define BLOCK 256
#define GRID 1536                // all co-resident (6 blocks/CU), zero tail
#define SPAN (GRID * BLOCK)      // 393216 threads; SPAN % E4 == 0 -> e4 fixed/thread
#define TOTAL4 (BB * VV * E4)    // 12,582,912 float4s
#define ITERS (TOTAL4 / SPAN)    // 32, exact

typedef float f4 __attribute__((ext_vector_type(4)));

__global__ __launch_bounds__(BLOCK) void bert_embed_kernel(
    const float* __restrict__ seq,     // [B, V, 3]
    const float* __restrict__ flux_w,  // [V, E]
    const float* __restrict__ flux_b,  // [V, E]
    const float* __restrict__ time_w,  // [V, E]
    const float* __restrict__ time_b,  // [V, E]
    float* __restrict__ out)           // [B, V, E]
{
    const int tid  = blockIdx.x * BLOCK + threadIdx.x;   // [0, SPAN)
    const int e4   = tid % E4;                           // fixed across iterations
    const int row0 = tid / E4;                           // [0, SPAN/E4) = [0, 2048)

    // div_term for pair indices 2*e4 (-> elems 4e4,4e4+1) and 2*e4+1
    // (-> 4e4+2,4e4+3), with 1/(2*pi) folded in: v_sin/v_cos take REVOLUTIONS.
    const float C1     = -0.011992630692677323f;   // -ln(10000)/768
    const float INV2PI = 0.15915494309189535f;
    const float d0 = __expf((float)(4 * e4) * C1) * INV2PI;
    const float d1 = __expf((float)(4 * e4 + 2) * C1) * INV2PI;

    const size_t ecol = (size_t)e4 * 4;

#pragma unroll 2
    for (int it = 0; it < ITERS; ++it) {
        // linear float4 index = tid + it*SPAN; row = b*VV + v walks monotonically.
        // row is wave-uniform (64-aligned lane spans nest inside 192-col rows);
        // the compiler scalarizes the seq loads on its own.
        int row = row0 + it * (SPAN / E4);               // [0, BB*VV)
        int v   = row & (VV - 1);
        int b   = row >> 12;                             // row / VV

        const float* sp = seq + ((size_t)b * VV + v) * 3;
        float s0 = sp[0];   // flux channel
        float s1 = sp[1];   // passend channel
        float s2 = sp[2];   // time channel

        const size_t we = (size_t)v * EE + ecol;
        f4 fw = *(const f4*)(flux_w + we);   // L3-resident after first batch slab
        f4 tw = *(const f4*)(time_w + we);
        f4 fb = *(const f4*)(flux_b + we);
        f4 tb = *(const f4*)(time_b + we);

        float r0  = s1 * d0;
        float r1  = s1 * d1;
        float sn0 = __builtin_amdgcn_sinf(r0);   // v_sin_f32 (revolutions)
        float cs0 = __builtin_amdgcn_cosf(r0);
        float sn1 = __builtin_amdgcn_sinf(r1);
        float cs1 = __builtin_amdgcn_cosf(r1);

        f4 o;
        o.x = fmaf(s0, fw.x, fmaf(s2, tw.x, fb.x + tb.x)) + sn0;
        o.y = fmaf(s0, fw.y, fmaf(s2, tw.y, fb.y + tb.y)) + cs0;
        o.z = fmaf(s0, fw.z, fmaf(s2, tw.z, fb.z + tb.z)) + sn1;
        o.w = fmaf(s0, fw.w, fmaf(s2, tw.w, fb.w + tb.w)) + cs1;

        // one monotone linear write stream across the whole grid:
        // block writes 4 KB contiguous per iteration, like the fill kernel
        __builtin_nontemporal_store(o, (f4*)(out + (size_t)row * EE + ecol));
    }
}

extern "C" void kernel_launch(void* const* d_in, const int* in_sizes, int n_in,
                              void* d_out, int out_size, void* d_ws, size_t ws_size,
                              hipStream_t stream) {
    const float* seq = (const float*)d_in[0];
    const float* fw  = (const float*)d_in[1];
    const float* fb  = (const float*)d_in[2];
    const float* tw  = (const float*)d_in[3];
    const float* tb  = (const float*)d_in[4];
    float* out = (float*)d_out;

    bert_embed_kernel<<<GRID, BLOCK, 0, stream>>>(seq, fw, fb, tw, tb, out);
}